// Round 14
// baseline (194.070 us; speedup 1.0000x reference)
//
#include <hip/hip_runtime.h>
#include <math.h>

#define B_   4
#define L_   4096
#define H_   8
#define D_   64
#define SK   45            // sample_k
#define NT   45            // n_top
#define BH   (B_*H_)       // 32
#define SCALE 0.125f       // 1/sqrt(64)
#define KC   256           // keys per attention chunk
#define JC2  16            // number of chunks
#define VCH  64            // L-rows per vmean chunk

typedef float vfloat4 __attribute__((ext_vector_type(4)));

// ---------------- Phase 1: M[b,h,q] = max_s(QK_s) - mean_s(QK_s) ----------------
// Wave = (b, half, qi-pair); 32B/lane; DPP-only 8-lane reduce; XCD-partitioned.
__global__ __launch_bounds__(256) void k_m(const float* __restrict__ q,
                                           const float* __restrict__ k,
                                           const int* __restrict__ samp,
                                           float* __restrict__ M) {
  __shared__ int sid[8 * SK];             // 360 ids (8 qi per block)
  const int ib   = blockIdx.x;            // 4096 blocks
  const int x    = ib & 7;
  const int b    = x >> 1;
  const int half = x & 1;
  const int qi_base = (ib >> 3) * 8;
  const int tid = threadIdx.x;
  for (int i = tid; i < 8 * SK; i += 256)
    sid[i] = samp[(size_t)qi_base * SK + i];
  __syncthreads();

  const int w    = tid >> 6;
  const int lane = tid & 63;
  const int g2   = lane >> 5;
  const int l32  = lane & 31;
  const int hg   = l32 >> 3;
  const int r8   = l32 & 7;
  const int qi   = qi_base + w * 2 + g2;
  const int wq   = w * 2 + g2;

  const float* qbase = q + (((size_t)b * L_ + qi) * H_ + half * 4 + hg) * D_ + r8 * 8;
  const vfloat4 qa = __builtin_nontemporal_load((const vfloat4*)qbase);
  const vfloat4 qb4 = __builtin_nontemporal_load((const vfloat4*)(qbase + 4));

  const int* myids = sid + wq * SK;
  const float* kb2 = k + (size_t)b * L_ * (H_ * D_) + (half * 4 + hg) * D_ + r8 * 8;

  float gmax = -1e30f, gsum = 0.f;
  #pragma unroll 5
  for (int s = 0; s < SK; ++s) {
    const int id = myids[s];
    const float* kr = kb2 + (size_t)id * (H_ * D_);
    const vfloat4 ka  = *(const vfloat4*)kr;
    const vfloat4 kbv = *(const vfloat4*)(kr + 4);
    float p = qa.x*ka.x + qa.y*ka.y + qa.z*ka.z + qa.w*ka.w
            + qb4.x*kbv.x + qb4.y*kbv.y + qb4.z*kbv.z + qb4.w*kbv.w;
    { int t = __builtin_amdgcn_mov_dpp(__float_as_int(p), 0xB1, 0xf, 0xf, true); p += __int_as_float(t); }
    { int t = __builtin_amdgcn_mov_dpp(__float_as_int(p), 0x4E, 0xf, 0xf, true); p += __int_as_float(t); }
    { int t = __builtin_amdgcn_mov_dpp(__float_as_int(p), 0x141, 0xf, 0xf, true); p += __int_as_float(t); }
    gmax = fmaxf(gmax, p);
    gsum += p;
  }
  if (r8 == 0) M[((size_t)b * 8 + half * 4 + hg) * L_ + qi] = gmax - gsum * (1.0f / SK);
}

// ---------------- Phase 2: top-45 of M per (b,h) via radix select ----------------
__global__ __launch_bounds__(256) void k_topk(const float* __restrict__ M,
                                              int* __restrict__ top) {
  __shared__ unsigned keys[L_];
  __shared__ unsigned hist[256];
  __shared__ unsigned wsum[4];
  __shared__ int sByte;
  __shared__ unsigned sAbove;
  __shared__ int cnt;
  const int bh = blockIdx.x, tid = threadIdx.x;
  const float* Mrow = M + (size_t)bh * L_;
  for (int i = tid; i < L_; i += 256) {
    const unsigned u = __float_as_uint(Mrow[i]);
    keys[i] = (u & 0x80000000u) ? ~u : (u | 0x80000000u);
  }
  unsigned prefix = 0u, fixed = 0u;
  unsigned remaining = NT;
  for (int p = 3; p >= 0; --p) {
    hist[tid] = 0u;
    __syncthreads();
    const int sh = p * 8;
    for (int i = tid; i < L_; i += 256) {
      const unsigned kk = keys[i];
      if ((kk & fixed) == prefix) atomicAdd(&hist[(kk >> sh) & 0xFFu], 1u);
    }
    __syncthreads();
    const int c = 255 - tid;
    const unsigned v = hist[c];
    unsigned x = v;
    #pragma unroll
    for (int o = 1; o < 64; o <<= 1) {
      const unsigned y = __shfl_up(x, o);
      if ((tid & 63) >= o) x += y;
    }
    if ((tid & 63) == 63) wsum[tid >> 6] = x;
    __syncthreads();
    unsigned off = 0;
    for (int w2 = 0; w2 < (tid >> 6); ++w2) off += wsum[w2];
    const unsigned Sincl = x + off;
    const unsigned Sab   = Sincl - v;
    if (Sab < remaining && remaining <= Sincl) { sByte = c; sAbove = Sab; }
    __syncthreads();
    prefix |= (unsigned)sByte << sh;
    fixed  |= 0xFFu << sh;
    remaining -= sAbove;
    __syncthreads();
  }
  if (tid == 0) cnt = 0;
  __syncthreads();
  int* trow = top + bh * NT;
  for (int i = tid; i < L_; i += 256) {
    if (keys[i] > prefix) { const int s = atomicAdd(&cnt, 1); trow[s] = i; }
  }
  __syncthreads();
  const int ngt = cnt;
  const int base = tid * 16;
  int lc = 0;
  #pragma unroll
  for (int j = 0; j < 16; ++j) lc += (keys[base + j] == prefix);
  unsigned x2 = (unsigned)lc;
  #pragma unroll
  for (int o = 1; o < 64; o <<= 1) {
    const unsigned y = __shfl_up(x2, o);
    if ((tid & 63) >= o) x2 += y;
  }
  if ((tid & 63) == 63) wsum[tid >> 6] = x2;
  __syncthreads();
  unsigned off2 = 0;
  for (int w2 = 0; w2 < (tid >> 6); ++w2) off2 += wsum[w2];
  unsigned rk = (x2 - (unsigned)lc) + off2;
  #pragma unroll
  for (int j = 0; j < 16; ++j) {
    if (keys[base + j] == prefix) {
      if (rk < remaining) trow[ngt + (int)rk] = base + j;
      ++rk;
    }
  }
}

// ---------------- V mean, stage 1 ----------------
__global__ __launch_bounds__(256) void k_vmean1(const float* __restrict__ v,
                                                float* __restrict__ vpart) {
  const int blk = blockIdx.x;
  const int b   = blk >> 6;
  const int c   = blk & 63;
  const int t   = threadIdx.x;
  const int hd4 = t & 127;
  const int p   = t >> 7;
  const float4* base = (const float4*)(v + ((size_t)b * L_ + (size_t)c * VCH) * (H_ * D_)) + hd4;
  float4 acc = {0.f, 0.f, 0.f, 0.f};
  for (int l = p; l < VCH; l += 2) {
    const float4 x = base[(size_t)l * 128];
    acc.x += x.x; acc.y += x.y; acc.z += x.z; acc.w += x.w;
  }
  __shared__ float4 s[2][128];
  s[p][hd4] = acc;
  __syncthreads();
  if (t < 128) {
    const float4 a = s[0][t], b2 = s[1][t];
    const float4 r = {a.x + b2.x, a.y + b2.y, a.z + b2.z, a.w + b2.w};
    ((float4*)vpart)[(size_t)blk * 128 + t] = r;
  }
}

// ---------------- V mean, stage 2 ----------------
__global__ __launch_bounds__(512) void k_vmean2(const float* __restrict__ vpart,
                                                float* __restrict__ vmean) {
  const int b = blockIdx.x, t = threadIdx.x;
  float acc = 0.f;
  for (int c = 0; c < 64; ++c)
    acc += vpart[((size_t)(b * 64 + c)) * 512 + t];
  vmean[b * 512 + t] = acc * (1.0f / L_);
}

// ---------------- fused attention: scores + chunk-softmax + PV partials ----------------
// block = (bh, jc), 512 threads (8 waves). Phase A: 2 lanes/key QK^T from LDS.
// Phase A2: chunk-local softmax (m_c, l_c per n-row). Phase B: PV partials,
// wave w owns n = w + 8t. Outputs: opart[bh][jc][45][64], ml[bh][jc][45][2].
__global__ __launch_bounds__(512) void k_attn(const float* __restrict__ q,
                                              const float* __restrict__ k,
                                              const float* __restrict__ v,
                                              const int* __restrict__ top,
                                              float* __restrict__ ml,
                                              float* __restrict__ opart) {
  __shared__ float lds_k[KC * 65];                  // 66.5 KB
  __shared__ float lds_p[NT * 260];                 // 46.8 KB  (260*4=1040B rows, 16B-aligned)
  __shared__ __align__(16) float lds_q[NT * 64];    // 11.5 KB
  __shared__ float lds_ml[NT * 2];
  const int bh = blockIdx.x >> 4, jc = blockIdx.x & 15;
  const int b = bh >> 3, h = bh & 7;
  const int tid = threadIdx.x;

  // stage K chunk [256][64]
  const float* kbase = k + (((size_t)b * L_ + jc * KC) * H_ + h) * D_;
  for (int fi = tid; fi < KC * 16; fi += 512) {
    const int j = fi >> 4, d4 = fi & 15;
    const float4 kv = *(const float4*)(kbase + (size_t)j * (H_ * D_) + d4 * 4);
    float* dst = &lds_k[j * 65 + d4 * 4];
    dst[0] = kv.x; dst[1] = kv.y; dst[2] = kv.z; dst[3] = kv.w;
  }
  // stage gathered Q_top
  for (int fi = tid; fi < NT * 64; fi += 512) {
    const int n = fi >> 6, d = fi & 63;
    const int qi = top[bh * NT + n];
    lds_q[fi] = q[(((size_t)b * L_ + qi) * H_ + h) * D_ + d];
  }
  __syncthreads();

  // Phase A: raw scaled scores -> lds_p[n][j]
  {
    const int j = tid >> 1, dh = tid & 1;
    float kr[32];
    const float* krow = &lds_k[j * 65 + dh * 32];
    #pragma unroll
    for (int t4 = 0; t4 < 8; ++t4) {
      const float4 kv = *(const float4*)(krow + t4 * 4);
      kr[t4*4+0] = kv.x; kr[t4*4+1] = kv.y; kr[t4*4+2] = kv.z; kr[t4*4+3] = kv.w;
    }
    for (int n = 0; n < NT; ++n) {
      const float* qrow = &lds_q[n * 64 + dh * 32];
      float s = 0.f;
      #pragma unroll
      for (int t4 = 0; t4 < 8; ++t4) {
        const float4 qq = *(const float4*)(qrow + t4 * 4);
        s += qq.x*kr[t4*4] + qq.y*kr[t4*4+1] + qq.z*kr[t4*4+2] + qq.w*kr[t4*4+3];
      }
      { int t = __builtin_amdgcn_mov_dpp(__float_as_int(s), 0xB1, 0xf, 0xf, true); s += __int_as_float(t); }
      if (dh == 0) lds_p[n * 260 + j] = s * SCALE;
    }
  }
  __syncthreads();

  // Phase A2: chunk-local softmax; wave w owns rows n = w, w+8, ...
  const int w = tid >> 6, lane = tid & 63;
  for (int n = w; n < NT; n += 8) {
    float* pr = &lds_p[n * 260];
    const float s0 = pr[lane], s1 = pr[64 + lane], s2 = pr[128 + lane], s3 = pr[192 + lane];
    float m = fmaxf(fmaxf(s0, s1), fmaxf(s2, s3));
    #pragma unroll
    for (int o = 1; o < 64; o <<= 1) m = fmaxf(m, __shfl_xor(m, o));
    const float p0 = __expf(s0 - m), p1 = __expf(s1 - m), p2 = __expf(s2 - m), p3 = __expf(s3 - m);
    float lsum = p0 + p1 + p2 + p3;
    #pragma unroll
    for (int o = 1; o < 64; o <<= 1) lsum += __shfl_xor(lsum, o);
    pr[lane] = p0; pr[64 + lane] = p1; pr[128 + lane] = p2; pr[192 + lane] = p3;
    if (lane == 0) { lds_ml[n * 2] = m; lds_ml[n * 2 + 1] = lsum; }
  }
  __syncthreads();

  // Phase B: PV partials; wave w owns n = w + 8t; lane = d
  const int d = lane;
  const int nn = (w < 5) ? 6 : 5;     // 45 = 5*6 + 3*5
  float acc[6];
  #pragma unroll
  for (int t = 0; t < 6; ++t) acc[t] = 0.f;
  const float* vbase = v + (((size_t)b * L_ + jc * KC) * H_ + h) * D_ + d;
  for (int j4 = 0; j4 < KC; j4 += 4) {
    float vv[4];
    #pragma unroll
    for (int u = 0; u < 4; ++u) vv[u] = vbase[(size_t)(j4 + u) * (H_ * D_)];
    #pragma unroll
    for (int t = 0; t < 6; ++t) {
      if (t < nn) {
        const int n = w + 8 * t;
        const float4 pv = *(const float4*)&lds_p[n * 260 + j4];
        acc[t] += pv.x * vv[0] + pv.y * vv[1] + pv.z * vv[2] + pv.w * vv[3];
      }
    }
  }
  float* obase = opart + (((size_t)bh * JC2 + jc) * NT) * 64;
  #pragma unroll
  for (int t = 0; t < 6; ++t)
    if (t < nn) obase[(w + 8 * t) * 64 + d] = acc[t];
  for (int i = tid; i < NT * 2; i += 512)
    ml[((size_t)bh * JC2 + jc) * (NT * 2) + i] = lds_ml[i];
}

// ---------------- fill output with broadcast V-mean ----------------
__global__ __launch_bounds__(256) void k_fill(const float* __restrict__ vmean,
                                              float* __restrict__ out) {
  const size_t i = (size_t)blockIdx.x * 256 + threadIdx.x;
  const int d4 = (int)(i & 15);
  const int bh = (int)(i >> 16);
  const float4* vm = (const float4*)(vmean + bh * D_);
  ((float4*)out)[i] = vm[d4];
}

// ---------------- combine chunk partials (softmax rescale) + scatter ----------------
__global__ void k_comb(const float* __restrict__ opart,
                       const float* __restrict__ ml,
                       const int* __restrict__ top,
                       float* __restrict__ out) {
  const int bhn = blockIdx.x, bh = bhn / NT, n = bhn % NT;
  const int d = threadIdx.x;
  float mc[JC2], lc[JC2];
  float mg = -1e30f;
  #pragma unroll
  for (int c = 0; c < JC2; ++c) {
    mc[c] = ml[((size_t)bh * JC2 + c) * (NT * 2) + n * 2];
    lc[c] = ml[((size_t)bh * JC2 + c) * (NT * 2) + n * 2 + 1];
    mg = fmaxf(mg, mc[c]);
  }
  float den = 0.f, num = 0.f;
  #pragma unroll
  for (int c = 0; c < JC2; ++c) {
    const float wgt = __expf(mc[c] - mg);
    den += wgt * lc[c];
    num += wgt * opart[(((size_t)bh * JC2 + c) * NT + n) * 64 + d];
  }
  const int qi = top[bh * NT + n];
  out[((size_t)bh * L_ + qi) * 64 + d] = num / den;
}

extern "C" void kernel_launch(void* const* d_in, const int* in_sizes, int n_in,
                              void* d_out, int out_size, void* d_ws, size_t ws_size,
                              hipStream_t stream) {
  const float* q    = (const float*)d_in[0];
  const float* k    = (const float*)d_in[1];
  const float* v    = (const float*)d_in[2];
  const int*   samp = (const int*)d_in[3];
  float* out = (float*)d_out;
  char*  ws  = (char*)d_ws;

  float* M     = (float*)ws;                 // 512 KB; reused as vpart, then ml
  int*   top   = (int*)(ws + 524288);
  float* vmean = (float*)(ws + 532480);
  float* opart = (float*)(ws + 540672);      // 5.9 MB
  float* vpart = M;                          // after k_topk
  float* ml    = M;                          // after k_vmean2 (184 KB <= 512 KB)

  hipLaunchKernelGGL(k_m,      dim3(BH * L_ / 32), dim3(256), 0, stream, q, k, samp, M);
  hipLaunchKernelGGL(k_topk,   dim3(BH),           dim3(256), 0, stream, M, top);
  hipLaunchKernelGGL(k_vmean1, dim3(B_ * 64),      dim3(256), 0, stream, v, vpart);
  hipLaunchKernelGGL(k_vmean2, dim3(B_),           dim3(512), 0, stream, vpart, vmean);
  hipLaunchKernelGGL(k_attn,   dim3(BH * JC2),     dim3(512), 0, stream, q, k, v, top, ml, opart);
  hipLaunchKernelGGL(k_fill,   dim3(8192),         dim3(256), 0, stream, vmean, out);
  hipLaunchKernelGGL(k_comb,   dim3(BH * NT),      dim3(64),  0, stream, opart, ml, top, out);
}

// Round 15
// 156.648 us; speedup vs baseline: 1.2389x; 1.2389x over previous
//
#include <hip/hip_runtime.h>
#include <math.h>

#define B_   4
#define L_   4096
#define H_   8
#define D_   64
#define SK   45            // sample_k
#define NT   45            // n_top
#define BH   (B_*H_)       // 32
#define SCALE 0.125f       // 1/sqrt(64)
#define KC   256           // keys per attention chunk
#define JC2  16            // number of chunks
#define VCH  64            // L-rows per vmean chunk

typedef float vfloat4 __attribute__((ext_vector_type(4)));

// ---------------- Phase 1: M[b,h,q] = max_s(QK_s) - mean_s(QK_s) ----------------
// Wave = (b, half, qi-pair); 32B/lane; DPP-only 8-lane reduce; XCD-partitioned.
__global__ __launch_bounds__(256) void k_m(const float* __restrict__ q,
                                           const float* __restrict__ k,
                                           const int* __restrict__ samp,
                                           float* __restrict__ M) {
  __shared__ int sid[8 * SK];             // 360 ids (8 qi per block)
  const int ib   = blockIdx.x;            // 4096 blocks
  const int x    = ib & 7;
  const int b    = x >> 1;
  const int half = x & 1;
  const int qi_base = (ib >> 3) * 8;
  const int tid = threadIdx.x;
  for (int i = tid; i < 8 * SK; i += 256)
    sid[i] = samp[(size_t)qi_base * SK + i];
  __syncthreads();

  const int w    = tid >> 6;
  const int lane = tid & 63;
  const int g2   = lane >> 5;
  const int l32  = lane & 31;
  const int hg   = l32 >> 3;
  const int r8   = l32 & 7;
  const int qi   = qi_base + w * 2 + g2;
  const int wq   = w * 2 + g2;

  const float* qbase = q + (((size_t)b * L_ + qi) * H_ + half * 4 + hg) * D_ + r8 * 8;
  const vfloat4 qa = __builtin_nontemporal_load((const vfloat4*)qbase);
  const vfloat4 qb4 = __builtin_nontemporal_load((const vfloat4*)(qbase + 4));

  const int* myids = sid + wq * SK;
  const float* kb2 = k + (size_t)b * L_ * (H_ * D_) + (half * 4 + hg) * D_ + r8 * 8;

  float gmax = -1e30f, gsum = 0.f;
  #pragma unroll 5
  for (int s = 0; s < SK; ++s) {
    const int id = myids[s];
    const float* kr = kb2 + (size_t)id * (H_ * D_);
    const vfloat4 ka  = *(const vfloat4*)kr;
    const vfloat4 kbv = *(const vfloat4*)(kr + 4);
    float p = qa.x*ka.x + qa.y*ka.y + qa.z*ka.z + qa.w*ka.w
            + qb4.x*kbv.x + qb4.y*kbv.y + qb4.z*kbv.z + qb4.w*kbv.w;
    { int t = __builtin_amdgcn_mov_dpp(__float_as_int(p), 0xB1, 0xf, 0xf, true); p += __int_as_float(t); }
    { int t = __builtin_amdgcn_mov_dpp(__float_as_int(p), 0x4E, 0xf, 0xf, true); p += __int_as_float(t); }
    { int t = __builtin_amdgcn_mov_dpp(__float_as_int(p), 0x141, 0xf, 0xf, true); p += __int_as_float(t); }
    gmax = fmaxf(gmax, p);
    gsum += p;
  }
  if (r8 == 0) M[((size_t)b * 8 + half * 4 + hg) * L_ + qi] = gmax - gsum * (1.0f / SK);
}

// ---------------- Phase 2: top-45 of M per (b,h) via radix select ----------------
__global__ __launch_bounds__(256) void k_topk(const float* __restrict__ M,
                                              int* __restrict__ top) {
  __shared__ unsigned keys[L_];
  __shared__ unsigned hist[256];
  __shared__ unsigned wsum[4];
  __shared__ int sByte;
  __shared__ unsigned sAbove;
  __shared__ int cnt;
  const int bh = blockIdx.x, tid = threadIdx.x;
  const float* Mrow = M + (size_t)bh * L_;
  for (int i = tid; i < L_; i += 256) {
    const unsigned u = __float_as_uint(Mrow[i]);
    keys[i] = (u & 0x80000000u) ? ~u : (u | 0x80000000u);
  }
  unsigned prefix = 0u, fixed = 0u;
  unsigned remaining = NT;
  for (int p = 3; p >= 0; --p) {
    hist[tid] = 0u;
    __syncthreads();
    const int sh = p * 8;
    for (int i = tid; i < L_; i += 256) {
      const unsigned kk = keys[i];
      if ((kk & fixed) == prefix) atomicAdd(&hist[(kk >> sh) & 0xFFu], 1u);
    }
    __syncthreads();
    const int c = 255 - tid;
    const unsigned v = hist[c];
    unsigned x = v;
    #pragma unroll
    for (int o = 1; o < 64; o <<= 1) {
      const unsigned y = __shfl_up(x, o);
      if ((tid & 63) >= o) x += y;
    }
    if ((tid & 63) == 63) wsum[tid >> 6] = x;
    __syncthreads();
    unsigned off = 0;
    for (int w2 = 0; w2 < (tid >> 6); ++w2) off += wsum[w2];
    const unsigned Sincl = x + off;
    const unsigned Sab   = Sincl - v;
    if (Sab < remaining && remaining <= Sincl) { sByte = c; sAbove = Sab; }
    __syncthreads();
    prefix |= (unsigned)sByte << sh;
    fixed  |= 0xFFu << sh;
    remaining -= sAbove;
    __syncthreads();
  }
  if (tid == 0) cnt = 0;
  __syncthreads();
  int* trow = top + bh * NT;
  for (int i = tid; i < L_; i += 256) {
    if (keys[i] > prefix) { const int s = atomicAdd(&cnt, 1); trow[s] = i; }
  }
  __syncthreads();
  const int ngt = cnt;
  const int base = tid * 16;
  int lc = 0;
  #pragma unroll
  for (int j = 0; j < 16; ++j) lc += (keys[base + j] == prefix);
  unsigned x2 = (unsigned)lc;
  #pragma unroll
  for (int o = 1; o < 64; o <<= 1) {
    const unsigned y = __shfl_up(x2, o);
    if ((tid & 63) >= o) x2 += y;
  }
  if ((tid & 63) == 63) wsum[tid >> 6] = x2;
  __syncthreads();
  unsigned off2 = 0;
  for (int w2 = 0; w2 < (tid >> 6); ++w2) off2 += wsum[w2];
  unsigned rk = (x2 - (unsigned)lc) + off2;
  #pragma unroll
  for (int j = 0; j < 16; ++j) {
    if (keys[base + j] == prefix) {
      if (rk < remaining) trow[ngt + (int)rk] = base + j;
      ++rk;
    }
  }
}

// ---------------- V mean, stage 1 ----------------
__global__ __launch_bounds__(256) void k_vmean1(const float* __restrict__ v,
                                                float* __restrict__ vpart) {
  const int blk = blockIdx.x;
  const int b   = blk >> 6;
  const int c   = blk & 63;
  const int t   = threadIdx.x;
  const int hd4 = t & 127;
  const int p   = t >> 7;
  const float4* base = (const float4*)(v + ((size_t)b * L_ + (size_t)c * VCH) * (H_ * D_)) + hd4;
  float4 acc = {0.f, 0.f, 0.f, 0.f};
  for (int l = p; l < VCH; l += 2) {
    const float4 x = base[(size_t)l * 128];
    acc.x += x.x; acc.y += x.y; acc.z += x.z; acc.w += x.w;
  }
  __shared__ float4 s[2][128];
  s[p][hd4] = acc;
  __syncthreads();
  if (t < 128) {
    const float4 a = s[0][t], b2 = s[1][t];
    const float4 r = {a.x + b2.x, a.y + b2.y, a.z + b2.z, a.w + b2.w};
    ((float4*)vpart)[(size_t)blk * 128 + t] = r;
  }
}

// ---------------- V mean, stage 2 ----------------
__global__ __launch_bounds__(512) void k_vmean2(const float* __restrict__ vpart,
                                                float* __restrict__ vmean) {
  const int b = blockIdx.x, t = threadIdx.x;
  float acc = 0.f;
  for (int c = 0; c < 64; ++c)
    acc += vpart[((size_t)(b * 64 + c)) * 512 + t];
  vmean[b * 512 + t] = acc * (1.0f / L_);
}

// ---------------- fused attention: scores + chunk-softmax + PV partials ----------------
// block = (bh, jc), 512 threads (8 waves), ~57 KB LDS -> 2 blocks/CU.
// Phase A: 2 lanes/key; K row loaded DIRECTLY global->regs (no LDS staging --
// each K element used by exactly one thread); Q_top stays in LDS (real reuse).
// Phase A2: chunk-local softmax. Phase B: PV partials (wave w owns n = w + 8t).
__global__ __launch_bounds__(512) void k_attn(const float* __restrict__ q,
                                              const float* __restrict__ k,
                                              const float* __restrict__ v,
                                              const int* __restrict__ top,
                                              float* __restrict__ ml,
                                              float* __restrict__ opart) {
  __shared__ float lds_p[NT * 260];                 // 46.8 KB (1040B rows, 16B-aligned)
  __shared__ __align__(16) float lds_q[NT * 64];    // 11.5 KB
  __shared__ float lds_ml[NT * 2];
  const int bh = blockIdx.x >> 4, jc = blockIdx.x & 15;
  const int b = bh >> 3, h = bh & 7;
  const int tid = threadIdx.x;

  // stage gathered Q_top
  for (int fi = tid; fi < NT * 64; fi += 512) {
    const int n = fi >> 6, d = fi & 63;
    const int qi = top[bh * NT + n];
    lds_q[fi] = q[(((size_t)b * L_ + qi) * H_ + h) * D_ + d];
  }
  __syncthreads();

  // Phase A: raw scaled scores -> lds_p[n][j]; K direct from global (L2)
  {
    const int j = tid >> 1, dh = tid & 1;
    const float* krow_g = k + (((size_t)b * L_ + jc * KC + j) * H_ + h) * D_ + dh * 32;
    float kr[32];
    #pragma unroll
    for (int t4 = 0; t4 < 8; ++t4) {
      const vfloat4 kv = *(const vfloat4*)(krow_g + t4 * 4);
      kr[t4*4+0] = kv.x; kr[t4*4+1] = kv.y; kr[t4*4+2] = kv.z; kr[t4*4+3] = kv.w;
    }
    for (int n = 0; n < NT; ++n) {
      const float* qrow = &lds_q[n * 64 + dh * 32];
      float s = 0.f;
      #pragma unroll
      for (int t4 = 0; t4 < 8; ++t4) {
        const float4 qq = *(const float4*)(qrow + t4 * 4);
        s += qq.x*kr[t4*4] + qq.y*kr[t4*4+1] + qq.z*kr[t4*4+2] + qq.w*kr[t4*4+3];
      }
      { int t = __builtin_amdgcn_mov_dpp(__float_as_int(s), 0xB1, 0xf, 0xf, true); s += __int_as_float(t); }
      if (dh == 0) lds_p[n * 260 + j] = s * SCALE;
    }
  }
  __syncthreads();

  // Phase A2: chunk-local softmax; wave w owns rows n = w, w+8, ...
  const int w = tid >> 6, lane = tid & 63;
  for (int n = w; n < NT; n += 8) {
    float* pr = &lds_p[n * 260];
    const float s0 = pr[lane], s1 = pr[64 + lane], s2 = pr[128 + lane], s3 = pr[192 + lane];
    float m = fmaxf(fmaxf(s0, s1), fmaxf(s2, s3));
    #pragma unroll
    for (int o = 1; o < 64; o <<= 1) m = fmaxf(m, __shfl_xor(m, o));
    const float p0 = __expf(s0 - m), p1 = __expf(s1 - m), p2 = __expf(s2 - m), p3 = __expf(s3 - m);
    float lsum = p0 + p1 + p2 + p3;
    #pragma unroll
    for (int o = 1; o < 64; o <<= 1) lsum += __shfl_xor(lsum, o);
    pr[lane] = p0; pr[64 + lane] = p1; pr[128 + lane] = p2; pr[192 + lane] = p3;
    if (lane == 0) { lds_ml[n * 2] = m; lds_ml[n * 2 + 1] = lsum; }
  }
  __syncthreads();

  // Phase B: PV partials; wave w owns n = w + 8t; lane = d
  const int d = lane;
  const int nn = (w < 5) ? 6 : 5;     // 45 = 5*6 + 3*5
  float acc[6];
  #pragma unroll
  for (int t = 0; t < 6; ++t) acc[t] = 0.f;
  const float* vbase = v + (((size_t)b * L_ + jc * KC) * H_ + h) * D_ + d;
  for (int j4 = 0; j4 < KC; j4 += 4) {
    float vv[4];
    #pragma unroll
    for (int u = 0; u < 4; ++u) vv[u] = vbase[(size_t)(j4 + u) * (H_ * D_)];
    #pragma unroll
    for (int t = 0; t < 6; ++t) {
      if (t < nn) {
        const int n = w + 8 * t;
        const float4 pv = *(const float4*)&lds_p[n * 260 + j4];
        acc[t] += pv.x * vv[0] + pv.y * vv[1] + pv.z * vv[2] + pv.w * vv[3];
      }
    }
  }
  float* obase = opart + (((size_t)bh * JC2 + jc) * NT) * 64;
  #pragma unroll
  for (int t = 0; t < 6; ++t)
    if (t < nn) obase[(w + 8 * t) * 64 + d] = acc[t];
  for (int i = tid; i < NT * 2; i += 512)
    ml[((size_t)bh * JC2 + jc) * (NT * 2) + i] = lds_ml[i];
}

// ---------------- fill output with broadcast V-mean ----------------
__global__ __launch_bounds__(256) void k_fill(const float* __restrict__ vmean,
                                              float* __restrict__ out) {
  const size_t i = (size_t)blockIdx.x * 256 + threadIdx.x;
  const int d4 = (int)(i & 15);
  const int bh = (int)(i >> 16);
  const float4* vm = (const float4*)(vmean + bh * D_);
  ((float4*)out)[i] = vm[d4];
}

// ---------------- combine chunk partials (softmax rescale) + scatter ----------------
__global__ void k_comb(const float* __restrict__ opart,
                       const float* __restrict__ ml,
                       const int* __restrict__ top,
                       float* __restrict__ out) {
  const int bhn = blockIdx.x, bh = bhn / NT, n = bhn % NT;
  const int d = threadIdx.x;
  float mc[JC2], lc[JC2];
  float mg = -1e30f;
  #pragma unroll
  for (int c = 0; c < JC2; ++c) {
    mc[c] = ml[((size_t)bh * JC2 + c) * (NT * 2) + n * 2];
    lc[c] = ml[((size_t)bh * JC2 + c) * (NT * 2) + n * 2 + 1];
    mg = fmaxf(mg, mc[c]);
  }
  float den = 0.f, num = 0.f;
  #pragma unroll
  for (int c = 0; c < JC2; ++c) {
    const float wgt = __expf(mc[c] - mg);
    den += wgt * lc[c];
    num += wgt * opart[(((size_t)bh * JC2 + c) * NT + n) * 64 + d];
  }
  const int qi = top[bh * NT + n];
  out[((size_t)bh * L_ + qi) * 64 + d] = num / den;
}

extern "C" void kernel_launch(void* const* d_in, const int* in_sizes, int n_in,
                              void* d_out, int out_size, void* d_ws, size_t ws_size,
                              hipStream_t stream) {
  const float* q    = (const float*)d_in[0];
  const float* k    = (const float*)d_in[1];
  const float* v    = (const float*)d_in[2];
  const int*   samp = (const int*)d_in[3];
  float* out = (float*)d_out;
  char*  ws  = (char*)d_ws;

  float* M     = (float*)ws;                 // 512 KB; reused as vpart, then ml
  int*   top   = (int*)(ws + 524288);
  float* vmean = (float*)(ws + 532480);
  float* opart = (float*)(ws + 540672);      // 5.9 MB
  float* vpart = M;                          // after k_topk
  float* ml    = M;                          // after k_vmean2 (184 KB <= 512 KB)

  hipLaunchKernelGGL(k_m,      dim3(BH * L_ / 32), dim3(256), 0, stream, q, k, samp, M);
  hipLaunchKernelGGL(k_topk,   dim3(BH),           dim3(256), 0, stream, M, top);
  hipLaunchKernelGGL(k_vmean1, dim3(B_ * 64),      dim3(256), 0, stream, v, vpart);
  hipLaunchKernelGGL(k_vmean2, dim3(B_),           dim3(512), 0, stream, vpart, vmean);
  hipLaunchKernelGGL(k_attn,   dim3(BH * JC2),     dim3(512), 0, stream, q, k, v, top, ml, opart);
  hipLaunchKernelGGL(k_fill,   dim3(8192),         dim3(256), 0, stream, vmean, out);
  hipLaunchKernelGGL(k_comb,   dim3(BH * NT),      dim3(64),  0, stream, opart, ml, top, out);
}

// Round 16
// 145.525 us; speedup vs baseline: 1.3336x; 1.0764x over previous
//
#include <hip/hip_runtime.h>
#include <math.h>

#define B_   4
#define L_   4096
#define H_   8
#define D_   64
#define SK   45            // sample_k
#define NT   45            // n_top
#define BH   (B_*H_)       // 32
#define SCALE 0.125f       // 1/sqrt(64)
#define KC   256           // keys per attention chunk
#define JC2  16            // number of chunks
#define VCH  64            // L-rows per vmean chunk

typedef float vfloat4 __attribute__((ext_vector_type(4)));

// ========== Launch 1: k_m (blocks 0..4095) + vmean1 (blocks 4096..4351) ==========
__global__ __launch_bounds__(256) void k_mv(const float* __restrict__ q,
                                            const float* __restrict__ k,
                                            const int* __restrict__ samp,
                                            const float* __restrict__ v,
                                            float* __restrict__ M,
                                            float* __restrict__ vpart) {
  const int tid = threadIdx.x;
  if (blockIdx.x < 4096) {
    // ---- k_m: M[b,h,q] = max_s - mean_s; XCD-partitioned L2 gather ----
    __shared__ int sid[8 * SK];
    const int ib   = blockIdx.x;
    const int x    = ib & 7;
    const int b    = x >> 1;
    const int half = x & 1;
    const int qi_base = (ib >> 3) * 8;
    for (int i = tid; i < 8 * SK; i += 256)
      sid[i] = samp[(size_t)qi_base * SK + i];
    __syncthreads();

    const int w    = tid >> 6;
    const int lane = tid & 63;
    const int g2   = lane >> 5;
    const int l32  = lane & 31;
    const int hg   = l32 >> 3;
    const int r8   = l32 & 7;
    const int qi   = qi_base + w * 2 + g2;
    const int wq   = w * 2 + g2;

    const float* qbase = q + (((size_t)b * L_ + qi) * H_ + half * 4 + hg) * D_ + r8 * 8;
    const vfloat4 qa = __builtin_nontemporal_load((const vfloat4*)qbase);
    const vfloat4 qb4 = __builtin_nontemporal_load((const vfloat4*)(qbase + 4));

    const int* myids = sid + wq * SK;
    const float* kb2 = k + (size_t)b * L_ * (H_ * D_) + (half * 4 + hg) * D_ + r8 * 8;

    float gmax = -1e30f, gsum = 0.f;
    #pragma unroll 5
    for (int s = 0; s < SK; ++s) {
      const int id = myids[s];
      const float* kr = kb2 + (size_t)id * (H_ * D_);
      const vfloat4 ka  = *(const vfloat4*)kr;
      const vfloat4 kbv = *(const vfloat4*)(kr + 4);
      float p = qa.x*ka.x + qa.y*ka.y + qa.z*ka.z + qa.w*ka.w
              + qb4.x*kbv.x + qb4.y*kbv.y + qb4.z*kbv.z + qb4.w*kbv.w;
      { int t = __builtin_amdgcn_mov_dpp(__float_as_int(p), 0xB1, 0xf, 0xf, true); p += __int_as_float(t); }
      { int t = __builtin_amdgcn_mov_dpp(__float_as_int(p), 0x4E, 0xf, 0xf, true); p += __int_as_float(t); }
      { int t = __builtin_amdgcn_mov_dpp(__float_as_int(p), 0x141, 0xf, 0xf, true); p += __int_as_float(t); }
      gmax = fmaxf(gmax, p);
      gsum += p;
    }
    if (r8 == 0) M[((size_t)b * 8 + half * 4 + hg) * L_ + qi] = gmax - gsum * (1.0f / SK);
  } else {
    // ---- vmean1: per-(b, L-chunk) partial sums (independent of k_m) ----
    const int blk = blockIdx.x - 4096;
    const int b   = blk >> 6;
    const int c   = blk & 63;
    const int hd4 = tid & 127;
    const int p   = tid >> 7;
    const float4* base = (const float4*)(v + ((size_t)b * L_ + (size_t)c * VCH) * (H_ * D_)) + hd4;
    float4 acc = {0.f, 0.f, 0.f, 0.f};
    for (int l = p; l < VCH; l += 2) {
      const float4 xv = base[(size_t)l * 128];
      acc.x += xv.x; acc.y += xv.y; acc.z += xv.z; acc.w += xv.w;
    }
    __shared__ float4 s[2][128];
    s[p][hd4] = acc;
    __syncthreads();
    if (tid < 128) {
      const float4 a = s[0][tid], b2 = s[1][tid];
      const float4 r = {a.x + b2.x, a.y + b2.y, a.z + b2.z, a.w + b2.w};
      ((float4*)vpart)[(size_t)blk * 128 + tid] = r;
    }
  }
}

// ========== Launch 2: radix top-45 (blocks 0..31) + vmean2 (blocks 32..35) ==========
__global__ __launch_bounds__(256) void k_topkv(const float* __restrict__ M,
                                               int* __restrict__ top,
                                               const float* __restrict__ vpart,
                                               float* __restrict__ vmean) {
  const int tid = threadIdx.x;
  if (blockIdx.x >= 32) {
    const int b = blockIdx.x - 32;
    for (int t = tid; t < 512; t += 256) {
      float acc = 0.f;
      for (int c = 0; c < 64; ++c)
        acc += vpart[((size_t)(b * 64 + c)) * 512 + t];
      vmean[b * 512 + t] = acc * (1.0f / L_);
    }
    return;
  }
  __shared__ unsigned keys[L_];
  __shared__ unsigned hist[256];
  __shared__ unsigned wsum[4];
  __shared__ int sByte;
  __shared__ unsigned sAbove;
  __shared__ int cnt;
  const int bh = blockIdx.x;
  const float* Mrow = M + (size_t)bh * L_;
  for (int i = tid; i < L_; i += 256) {
    const unsigned u = __float_as_uint(Mrow[i]);
    keys[i] = (u & 0x80000000u) ? ~u : (u | 0x80000000u);
  }
  unsigned prefix = 0u, fixed = 0u;
  unsigned remaining = NT;
  for (int p = 3; p >= 0; --p) {
    hist[tid] = 0u;
    __syncthreads();
    const int sh = p * 8;
    for (int i = tid; i < L_; i += 256) {
      const unsigned kk = keys[i];
      if ((kk & fixed) == prefix) atomicAdd(&hist[(kk >> sh) & 0xFFu], 1u);
    }
    __syncthreads();
    const int c = 255 - tid;
    const unsigned v = hist[c];
    unsigned x = v;
    #pragma unroll
    for (int o = 1; o < 64; o <<= 1) {
      const unsigned y = __shfl_up(x, o);
      if ((tid & 63) >= o) x += y;
    }
    if ((tid & 63) == 63) wsum[tid >> 6] = x;
    __syncthreads();
    unsigned off = 0;
    for (int w2 = 0; w2 < (tid >> 6); ++w2) off += wsum[w2];
    const unsigned Sincl = x + off;
    const unsigned Sab   = Sincl - v;
    if (Sab < remaining && remaining <= Sincl) { sByte = c; sAbove = Sab; }
    __syncthreads();
    prefix |= (unsigned)sByte << sh;
    fixed  |= 0xFFu << sh;
    remaining -= sAbove;
    __syncthreads();
  }
  if (tid == 0) cnt = 0;
  __syncthreads();
  int* trow = top + bh * NT;
  for (int i = tid; i < L_; i += 256) {
    if (keys[i] > prefix) { const int s = atomicAdd(&cnt, 1); trow[s] = i; }
  }
  __syncthreads();
  const int ngt = cnt;
  const int base = tid * 16;
  int lc = 0;
  #pragma unroll
  for (int j = 0; j < 16; ++j) lc += (keys[base + j] == prefix);
  unsigned x2 = (unsigned)lc;
  #pragma unroll
  for (int o = 1; o < 64; o <<= 1) {
    const unsigned y = __shfl_up(x2, o);
    if ((tid & 63) >= o) x2 += y;
  }
  if ((tid & 63) == 63) wsum[tid >> 6] = x2;
  __syncthreads();
  unsigned off2 = 0;
  for (int w2 = 0; w2 < (tid >> 6); ++w2) off2 += wsum[w2];
  unsigned rk = (x2 - (unsigned)lc) + off2;
  #pragma unroll
  for (int j = 0; j < 16; ++j) {
    if (keys[base + j] == prefix) {
      if (rk < remaining) trow[ngt + (int)rk] = base + j;
      ++rk;
    }
  }
}

// ========== Launch 3: fused attention (blocks 0..511) + vmean fill (512..4607) ==========
__global__ __launch_bounds__(512) void k_attnf(const float* __restrict__ q,
                                               const float* __restrict__ k,
                                               const float* __restrict__ v,
                                               const int* __restrict__ top,
                                               const float* __restrict__ vmean,
                                               float* __restrict__ ml,
                                               float* __restrict__ opart,
                                               float* __restrict__ out) {
  __shared__ float lds_p[NT * 260];                 // 46.8 KB
  __shared__ __align__(16) float lds_q[NT * 64];    // 11.5 KB
  __shared__ float lds_ml[NT * 2];
  const int tid = threadIdx.x;
  if (blockIdx.x >= 512) {
    // ---- fill: broadcast V-mean into all output rows ----
    const size_t i = (size_t)(blockIdx.x - 512) * 512 + tid;  // float4 index
    const int d4 = (int)(i & 15);
    const int bh = (int)(i >> 16);
    const float4* vm = (const float4*)(vmean + bh * D_);
    ((float4*)out)[i] = vm[d4];
    return;
  }
  const int bh = blockIdx.x >> 4, jc = blockIdx.x & 15;
  const int b = bh >> 3, h = bh & 7;

  for (int fi = tid; fi < NT * 64; fi += 512) {
    const int n = fi >> 6, d = fi & 63;
    const int qi = top[bh * NT + n];
    lds_q[fi] = q[(((size_t)b * L_ + qi) * H_ + h) * D_ + d];
  }
  __syncthreads();

  // Phase A: scores -> lds_p; K direct global->regs (no reuse, skip LDS)
  {
    const int j = tid >> 1, dh = tid & 1;
    const float* krow_g = k + (((size_t)b * L_ + jc * KC + j) * H_ + h) * D_ + dh * 32;
    float kr[32];
    #pragma unroll
    for (int t4 = 0; t4 < 8; ++t4) {
      const vfloat4 kv = *(const vfloat4*)(krow_g + t4 * 4);
      kr[t4*4+0] = kv.x; kr[t4*4+1] = kv.y; kr[t4*4+2] = kv.z; kr[t4*4+3] = kv.w;
    }
    __builtin_amdgcn_s_setprio(1);
    for (int n = 0; n < NT; ++n) {
      const float* qrow = &lds_q[n * 64 + dh * 32];
      float s = 0.f;
      #pragma unroll
      for (int t4 = 0; t4 < 8; ++t4) {
        const float4 qq = *(const float4*)(qrow + t4 * 4);
        s += qq.x*kr[t4*4] + qq.y*kr[t4*4+1] + qq.z*kr[t4*4+2] + qq.w*kr[t4*4+3];
      }
      { int t = __builtin_amdgcn_mov_dpp(__float_as_int(s), 0xB1, 0xf, 0xf, true); s += __int_as_float(t); }
      if (dh == 0) lds_p[n * 260 + j] = s * SCALE;
    }
    __builtin_amdgcn_s_setprio(0);
  }
  __syncthreads();

  // Phase A2: chunk-local softmax; wave w owns rows n = w, w+8, ...
  const int w = tid >> 6, lane = tid & 63;
  for (int n = w; n < NT; n += 8) {
    float* pr = &lds_p[n * 260];
    const float s0 = pr[lane], s1 = pr[64 + lane], s2 = pr[128 + lane], s3 = pr[192 + lane];
    float m = fmaxf(fmaxf(s0, s1), fmaxf(s2, s3));
    #pragma unroll
    for (int o = 1; o < 64; o <<= 1) m = fmaxf(m, __shfl_xor(m, o));
    const float p0 = __expf(s0 - m), p1 = __expf(s1 - m), p2 = __expf(s2 - m), p3 = __expf(s3 - m);
    float lsum = p0 + p1 + p2 + p3;
    #pragma unroll
    for (int o = 1; o < 64; o <<= 1) lsum += __shfl_xor(lsum, o);
    pr[lane] = p0; pr[64 + lane] = p1; pr[128 + lane] = p2; pr[192 + lane] = p3;
    if (lane == 0) { lds_ml[n * 2] = m; lds_ml[n * 2 + 1] = lsum; }
  }
  __syncthreads();

  // Phase B: PV partials; wave w owns n = w + 8t; lane = d
  const int d = lane;
  const int nn = (w < 5) ? 6 : 5;
  float acc[6];
  #pragma unroll
  for (int t = 0; t < 6; ++t) acc[t] = 0.f;
  const float* vbase = v + (((size_t)b * L_ + jc * KC) * H_ + h) * D_ + d;
  __builtin_amdgcn_s_setprio(1);
  for (int j4 = 0; j4 < KC; j4 += 4) {
    float vv[4];
    #pragma unroll
    for (int u = 0; u < 4; ++u) vv[u] = vbase[(size_t)(j4 + u) * (H_ * D_)];
    #pragma unroll
    for (int t = 0; t < 6; ++t) {
      if (t < nn) {
        const int n = w + 8 * t;
        const float4 pv = *(const float4*)&lds_p[n * 260 + j4];
        acc[t] += pv.x * vv[0] + pv.y * vv[1] + pv.z * vv[2] + pv.w * vv[3];
      }
    }
  }
  __builtin_amdgcn_s_setprio(0);
  float* obase = opart + (((size_t)bh * JC2 + jc) * NT) * 64;
  #pragma unroll
  for (int t = 0; t < 6; ++t)
    if (t < nn) obase[(w + 8 * t) * 64 + d] = acc[t];
  for (int i = tid; i < NT * 2; i += 512)
    ml[((size_t)bh * JC2 + jc) * (NT * 2) + i] = lds_ml[i];
}

// ========== Launch 4: combine chunk partials + scatter ==========
__global__ void k_comb(const float* __restrict__ opart,
                       const float* __restrict__ ml,
                       const int* __restrict__ top,
                       float* __restrict__ out) {
  const int bhn = blockIdx.x, bh = bhn / NT, n = bhn % NT;
  const int d = threadIdx.x;
  float mc[JC2], lc[JC2];
  float mg = -1e30f;
  #pragma unroll
  for (int c = 0; c < JC2; ++c) {
    mc[c] = ml[((size_t)bh * JC2 + c) * (NT * 2) + n * 2];
    lc[c] = ml[((size_t)bh * JC2 + c) * (NT * 2) + n * 2 + 1];
    mg = fmaxf(mg, mc[c]);
  }
  float den = 0.f, num = 0.f;
  #pragma unroll
  for (int c = 0; c < JC2; ++c) {
    const float wgt = __expf(mc[c] - mg);
    den += wgt * lc[c];
    num += wgt * opart[(((size_t)bh * JC2 + c) * NT + n) * 64 + d];
  }
  const int qi = top[bh * NT + n];
  out[((size_t)bh * L_ + qi) * 64 + d] = num / den;
}

extern "C" void kernel_launch(void* const* d_in, const int* in_sizes, int n_in,
                              void* d_out, int out_size, void* d_ws, size_t ws_size,
                              hipStream_t stream) {
  const float* q    = (const float*)d_in[0];
  const float* k    = (const float*)d_in[1];
  const float* v    = (const float*)d_in[2];
  const int*   samp = (const int*)d_in[3];
  float* out = (float*)d_out;
  char*  ws  = (char*)d_ws;

  float* M     = (float*)ws;                 // 512 KB; reused as ml after topk
  int*   top   = (int*)(ws + 524288);
  float* vmean = (float*)(ws + 532480);
  float* opart = (float*)(ws + 540672);      // 5.9 MB (written in launch 3)
  float* vpart = opart;                      // launches 1-2 only; dead before opart is written
  float* ml    = M;                          // M dead after launch 2

  hipLaunchKernelGGL(k_mv,    dim3(4096 + 256),  dim3(256), 0, stream, q, k, samp, v, M, vpart);
  hipLaunchKernelGGL(k_topkv, dim3(36),          dim3(256), 0, stream, M, top, vpart, vmean);
  hipLaunchKernelGGL(k_attnf, dim3(512 + 4096),  dim3(512), 0, stream, q, k, v, top, vmean, ml, opart, out);
  hipLaunchKernelGGL(k_comb,  dim3(BH * NT),     dim3(64),  0, stream, opart, ml, top, out);
}